// Round 9
// baseline (95.624 us; speedup 1.0000x reference)
//
#include <hip/hip_runtime.h>

#define B 128
#define L 1024

#if __has_builtin(__builtin_amdgcn_exp2f)
#define EXP2(x) __builtin_amdgcn_exp2f(x)
#else
#define EXP2(x) __expf((x) * 0.6931471805599453f)
#endif

// ws layout (floats):
//   [0..2048)  per-wave dcg partials: idx = blk*2 + wave  (blk = b*8+iseg)
//   [2048]     ndcg accumulator      (zeroed by pair_kernel block 0)
//   [2049]     completion counter    (zeroed by pair_kernel block 0)
#define WS_ACC  2048
#define WS_GCTR 2049

// Phi(diff/sqrt2) via erf(y), y = diff/2:
//   erfc(|y|) ~= exp(-(1.12838 y + 0.6446 y^2 + 0.0745 y^3)), |dPhi| <= ~2.5e-4
// Constants pre-multiplied by -log2(e) for v_exp_f32.
// pj arrives RAW from an SGPR (scalar-mem path); the 0.5 prescale is folded
// into one v_fma: d = fma(-0.5, pj_raw, pi_half).
// Per pair: fma, fma, fma, mul, exp2, sub, bfi, add = 7 full-rate + 1 trans.
#define K1 -1.6279072f
#define K2 -0.9299637f
#define K3 -0.1074808f

__device__ __forceinline__ float erf_term(float pi_half, float pj_raw) {
    float d = __builtin_fmaf(-0.5f, pj_raw, pi_half);
    float a = __builtin_fabsf(d);
    float t = __builtin_fmaf(K3, a, K2);
    float u = __builtin_fmaf(t, a, K1);
    float e = EXP2(a * u);                   // ~= erfc(|y|)
    return __builtin_copysignf(1.0f - e, d); // = erf(y)
}

// grid = B*8 blocks, 256 threads, 4 blocks/CU -> 4 waves/SIMD.
// Block (b, iseg) owns 128 i's; thread (il = tid&127, jh = tid>>7) sums its
// 512-j half. KEY CHANGE (R8 lesson): j-values are wave-uniform, so they are
// read via block-uniform global indices -> compiler emits s_load_dwordx4
// (scalar-mem pipe). NO LDS in the hot loop — the old uniform-address
// ds_read_b128 wasted the per-CU LDS pipe (16B useful per ~12-cycle op) and
// capped VALUBusy at ~50%. NO atomics/fences here (R6 lesson).
__global__ __launch_bounds__(256, 8) void pair_kernel(const float* __restrict__ preds,
                                                      const float* __restrict__ target,
                                                      float* __restrict__ ws) {
    __shared__ float red[256];              // cross-half E reduction only

    const int blk  = blockIdx.x;
    const int b    = blk >> 3;
    const int iseg = blk & 7;
    const int tid  = threadIdx.x;
    const int il   = tid & 127;             // i_local
    const int jh   = tid >> 7;              // j half (0/1)

    if (blk == 0 && tid == 0) {
        ws[WS_ACC] = 0.0f;                  // visible to finish_kernel at
        ((int*)ws)[WS_GCTR] = 0;            // dispatch boundary
    }

    const float* prow = preds + b * L;
    const int i = iseg * 128 + il;

    const float pi_half = 0.5f * prow[i];                      // per-lane
    const float tgt = (tid < 128) ? target[b * L + i] : 0.0f;  // hoisted

    // j-half base: block-uniform pointer; loop index uniform -> scalar loads
    const float4* pj4 = reinterpret_cast<const float4*>(prow + jh * 512);

    float a0 = 0.f, a1 = 0.f, a2 = 0.f, a3 = 0.f,
          a4 = 0.f, a5 = 0.f, a6 = 0.f, a7 = 0.f;
    for (int j4 = 0; j4 < 128; j4 += 4) {    // 16 j's per iteration
        float4 q0 = pj4[j4 + 0];
        float4 q1 = pj4[j4 + 1];
        float4 q2 = pj4[j4 + 2];
        float4 q3 = pj4[j4 + 3];
        a0 += erf_term(pi_half, q0.x);
        a1 += erf_term(pi_half, q0.y);
        a2 += erf_term(pi_half, q0.z);
        a3 += erf_term(pi_half, q0.w);
        a4 += erf_term(pi_half, q1.x);
        a5 += erf_term(pi_half, q1.y);
        a6 += erf_term(pi_half, q1.z);
        a7 += erf_term(pi_half, q1.w);
        a0 += erf_term(pi_half, q2.x);
        a1 += erf_term(pi_half, q2.y);
        a2 += erf_term(pi_half, q2.z);
        a3 += erf_term(pi_half, q2.w);
        a4 += erf_term(pi_half, q3.x);
        a5 += erf_term(pi_half, q3.y);
        a6 += erf_term(pi_half, q3.z);
        a7 += erf_term(pi_half, q3.w);
    }
    float E = ((a0 + a1) + (a2 + a3)) + ((a4 + a5) + (a6 + a7));

    // cross-half combine in LDS; lower 128 threads (2 waves) finish the i's
    red[tid] = E;
    __syncthreads();

    if (tid < 128) {
        float Es = red[tid] + red[tid + 128];
        // sum_j Phi = L/2 + Es/2 (diag contributes exactly 0.5); er+1 = 513.5 + Es/2
        float er1 = 513.5f + 0.5f * Es;
        float g = EXP2(tgt) - 1.0f;          // 2^t - 1, exact for integer grades
        float contrib = g * __builtin_amdgcn_rcpf(__log2f(er1));
        #pragma unroll
        for (int off = 32; off > 0; off >>= 1)
            contrib += __shfl_down(contrib, off);
        if ((tid & 63) == 0)
            ws[blk * 2 + (tid >> 6)] = contrib;   // plain store, disjoint slot
    }
}

// grid = B blocks, 256 threads. Block b: combine 16 dcg partials, counting-sort
// IDCG (grades are ints 0..4), ndcg; last block writes the final scalar.
__global__ __launch_bounds__(256) void finish_kernel(const float* __restrict__ target,
                                                     float* __restrict__ ws,
                                                     float* __restrict__ out) {
    __shared__ unsigned long long cred[256];
    __shared__ float2 fred[256];

    const int b   = blockIdx.x;
    const int tid = threadIdx.x;
    const float* trow = target + b * L;

    // packed 16-bit counts of grades >=4,>=3,>=2,>=1 (max 1024 fits)
    unsigned long long cnt = 0ull;
    #pragma unroll
    for (int k = 0; k < 4; ++k) {
        float t = trow[tid + k * 256];
        cnt += ((unsigned long long)(t > 3.5f) << 48)
             + ((unsigned long long)(t > 2.5f) << 32)
             + ((unsigned long long)(t > 1.5f) << 16)
             + ((unsigned long long)(t > 0.5f));
    }
    cred[tid] = cnt;
    __syncthreads();
    #pragma unroll
    for (int s = 128; s > 0; s >>= 1) {
        if (tid < (unsigned)s) cred[tid] += cred[tid + s];
        __syncthreads();
    }
    unsigned long long tot = cred[0];
    const int n4 = (int)(tot >> 48) & 0xFFFF;
    const int n3 = (int)(tot >> 32) & 0xFFFF;
    const int n2 = (int)(tot >> 16) & 0xFFFF;
    const int n1 = (int)(tot)       & 0xFFFF;

    // parallel IDCG; joint reduction with the 16 dcg partials of this row
    float idcg_p = 0.0f;
    #pragma unroll
    for (int k = 0; k < 4; ++k) {
        int pos = tid + 1 + k * 256;
        float gain = (pos <= n4) ? 15.0f : (pos <= n3) ? 7.0f :
                     (pos <= n2) ? 3.0f  : (pos <= n1) ? 1.0f : 0.0f;
        idcg_p += gain * __builtin_amdgcn_rcpf(__log2f((float)pos + 1.0f));
    }
    float dcg_p = (tid < 16) ? ws[b * 16 + tid] : 0.0f;
    fred[tid] = make_float2(idcg_p, dcg_p);
    __syncthreads();
    #pragma unroll
    for (int s = 128; s > 0; s >>= 1) {
        if (tid < (unsigned)s) {
            float2 x = fred[tid], y = fred[tid + s];
            fred[tid] = make_float2(x.x + y.x, x.y + y.y);
        }
        __syncthreads();
    }

    if (tid == 0) {
        float ndcg = fred[0].y / (fred[0].x + 1e-10f);
        atomicAdd(&ws[WS_ACC], ndcg);
        __threadfence();
        int old = atomicAdd((int*)ws + WS_GCTR, 1);
        if (old == B - 1) {
            float acc = atomicAdd(&ws[WS_ACC], 0.0f);  // coherent read
            out[0] = -acc * (1.0f / (float)B);
        }
    }
}

extern "C" void kernel_launch(void* const* d_in, const int* in_sizes, int n_in,
                              void* d_out, int out_size, void* d_ws, size_t ws_size,
                              hipStream_t stream) {
    const float* preds  = (const float*)d_in[0];
    const float* target = (const float*)d_in[1];
    float* out = (float*)d_out;
    float* ws  = (float*)d_ws;

    pair_kernel<<<B * 8, 256, 0, stream>>>(preds, target, ws);
    finish_kernel<<<B, 256, 0, stream>>>(target, ws, out);
}

// Round 10
// 93.330 us; speedup vs baseline: 1.0246x; 1.0246x over previous
//
#include <hip/hip_runtime.h>

#define B 128
#define L 1024

#if __has_builtin(__builtin_amdgcn_exp2f)
#define EXP2(x) __builtin_amdgcn_exp2f(x)
#else
#define EXP2(x) __expf((x) * 0.6931471805599453f)
#endif

// ws layout (floats):
//   [0..2048)  per-block dcg partials: idx = blk = b*16 + seg
//   [2048]     ndcg accumulator      (zeroed by pair_kernel block 0)
//   [2049]     completion counter    (zeroed by pair_kernel block 0)
#define WS_ACC  2048
#define WS_GCTR 2049

// Phi(diff/sqrt2) via erf(y), y = diff/2:
//   erfc(|y|) ~= exp(-(1.12838 y + 0.6446 y^2 + 0.0745 y^3)), |dPhi| <= ~2.5e-4
// Constants pre-multiplied by -log2(e) for v_exp_f32.
// Per pair: fma, abs, fma, fma, mul, exp2(~8 slots, quarter-rate), sub, bfi,
// add ~= 15 lane-slots -> 25.6 us of pure ALU work for 134M pairs (measured
// VALU busy-time matches: R9 41.2us x 60% = 24.7us). The gap to close is
// issue efficiency, hence 32 waves/CU this round.
#define K1 -1.6279072f
#define K2 -0.9299637f
#define K3 -0.1074808f

__device__ __forceinline__ float erf_term(float pi_half, float pj_raw) {
    float d = __builtin_fmaf(-0.5f, pj_raw, pi_half);
    float a = __builtin_fabsf(d);
    float t = __builtin_fmaf(K3, a, K2);
    float u = __builtin_fmaf(t, a, K1);
    float e = EXP2(a * u);                   // ~= erfc(|y|)
    return __builtin_copysignf(1.0f - e, d); // = erf(y)
}

// grid = B*16 blocks, 256 threads -> 8 blocks/CU -> 32 waves/CU (100% wave
// occupancy; R9 had 16 and stalled at 60% VALUBusy on exp dep-chains).
// Block (b, seg) owns 64 i's; thread (il = tid&63, jq = tid>>6) sums its
// 256-j quarter. Within a wave the j-pointer is uniform (R9 load path).
// Cross-quarter combine in LDS at the end (intra-block — R6 lesson).
// NO atomics/fences in the hot path; one plain store per block.
__global__ __launch_bounds__(256, 8) void pair_kernel(const float* __restrict__ preds,
                                                      const float* __restrict__ target,
                                                      float* __restrict__ ws) {
    __shared__ float red[256];              // cross-quarter E reduction

    const int blk = blockIdx.x;
    const int b   = blk >> 4;
    const int seg = blk & 15;
    const int tid = threadIdx.x;
    const int il  = tid & 63;               // i_lane
    const int jq  = tid >> 6;               // j quarter (0..3) == wave id

    if (blk == 0 && tid == 0) {
        ws[WS_ACC] = 0.0f;                  // visible to finish_kernel at
        ((int*)ws)[WS_GCTR] = 0;            // dispatch boundary
    }

    const float* prow = preds + b * L;
    const int i = seg * 64 + il;

    const float pi_half = 0.5f * prow[i];                      // per-lane
    const float tgt = (tid < 64) ? target[b * L + seg * 64 + tid] : 0.0f;

    // j-quarter base: wave-uniform pointer -> scalar/broadcast loads
    const float4* pj4 = reinterpret_cast<const float4*>(prow + jq * 256);

    float a0 = 0.f, a1 = 0.f, a2 = 0.f, a3 = 0.f,
          a4 = 0.f, a5 = 0.f, a6 = 0.f, a7 = 0.f;
    for (int j4 = 0; j4 < 64; j4 += 4) {     // 16 j's per iteration
        float4 q0 = pj4[j4 + 0];
        float4 q1 = pj4[j4 + 1];
        float4 q2 = pj4[j4 + 2];
        float4 q3 = pj4[j4 + 3];
        a0 += erf_term(pi_half, q0.x);
        a1 += erf_term(pi_half, q0.y);
        a2 += erf_term(pi_half, q0.z);
        a3 += erf_term(pi_half, q0.w);
        a4 += erf_term(pi_half, q1.x);
        a5 += erf_term(pi_half, q1.y);
        a6 += erf_term(pi_half, q1.z);
        a7 += erf_term(pi_half, q1.w);
        a0 += erf_term(pi_half, q2.x);
        a1 += erf_term(pi_half, q2.y);
        a2 += erf_term(pi_half, q2.z);
        a3 += erf_term(pi_half, q2.w);
        a4 += erf_term(pi_half, q3.x);
        a5 += erf_term(pi_half, q3.y);
        a6 += erf_term(pi_half, q3.z);
        a7 += erf_term(pi_half, q3.w);
    }
    float E = ((a0 + a1) + (a2 + a3)) + ((a4 + a5) + (a6 + a7));

    // cross-quarter combine in LDS; wave 0 finishes the 64 i's
    red[tid] = E;
    __syncthreads();

    if (tid < 64) {
        float Es = (red[tid] + red[tid + 64]) + (red[tid + 128] + red[tid + 192]);
        // sum_j Phi = L/2 + Es/2 (diag contributes exactly 0.5); er+1 = 513.5 + Es/2
        float er1 = 513.5f + 0.5f * Es;
        float g = EXP2(tgt) - 1.0f;          // 2^t - 1, exact for integer grades
        float contrib = g * __builtin_amdgcn_rcpf(__log2f(er1));
        #pragma unroll
        for (int off = 32; off > 0; off >>= 1)
            contrib += __shfl_down(contrib, off);
        if (tid == 0)
            ws[blk] = contrib;               // plain store, disjoint slot
    }
}

// grid = B blocks, 256 threads. Block b: combine 16 dcg partials, counting-sort
// IDCG (grades are ints 0..4), ndcg; last block writes the final scalar.
__global__ __launch_bounds__(256) void finish_kernel(const float* __restrict__ target,
                                                     float* __restrict__ ws,
                                                     float* __restrict__ out) {
    __shared__ unsigned long long cred[256];
    __shared__ float2 fred[256];

    const int b   = blockIdx.x;
    const int tid = threadIdx.x;
    const float* trow = target + b * L;

    // packed 16-bit counts of grades >=4,>=3,>=2,>=1 (max 1024 fits)
    unsigned long long cnt = 0ull;
    #pragma unroll
    for (int k = 0; k < 4; ++k) {
        float t = trow[tid + k * 256];
        cnt += ((unsigned long long)(t > 3.5f) << 48)
             + ((unsigned long long)(t > 2.5f) << 32)
             + ((unsigned long long)(t > 1.5f) << 16)
             + ((unsigned long long)(t > 0.5f));
    }
    cred[tid] = cnt;
    __syncthreads();
    #pragma unroll
    for (int s = 128; s > 0; s >>= 1) {
        if (tid < (unsigned)s) cred[tid] += cred[tid + s];
        __syncthreads();
    }
    unsigned long long tot = cred[0];
    const int n4 = (int)(tot >> 48) & 0xFFFF;
    const int n3 = (int)(tot >> 32) & 0xFFFF;
    const int n2 = (int)(tot >> 16) & 0xFFFF;
    const int n1 = (int)(tot)       & 0xFFFF;

    // parallel IDCG; joint reduction with the 16 dcg partials of this row
    float idcg_p = 0.0f;
    #pragma unroll
    for (int k = 0; k < 4; ++k) {
        int pos = tid + 1 + k * 256;
        float gain = (pos <= n4) ? 15.0f : (pos <= n3) ? 7.0f :
                     (pos <= n2) ? 3.0f  : (pos <= n1) ? 1.0f : 0.0f;
        idcg_p += gain * __builtin_amdgcn_rcpf(__log2f((float)pos + 1.0f));
    }
    float dcg_p = (tid < 16) ? ws[b * 16 + tid] : 0.0f;
    fred[tid] = make_float2(idcg_p, dcg_p);
    __syncthreads();
    #pragma unroll
    for (int s = 128; s > 0; s >>= 1) {
        if (tid < (unsigned)s) {
            float2 x = fred[tid], y = fred[tid + s];
            fred[tid] = make_float2(x.x + y.x, x.y + y.y);
        }
        __syncthreads();
    }

    if (tid == 0) {
        float ndcg = fred[0].y / (fred[0].x + 1e-10f);
        atomicAdd(&ws[WS_ACC], ndcg);
        __threadfence();
        int old = atomicAdd((int*)ws + WS_GCTR, 1);
        if (old == B - 1) {
            float acc = atomicAdd(&ws[WS_ACC], 0.0f);  // coherent read
            out[0] = -acc * (1.0f / (float)B);
        }
    }
}

extern "C" void kernel_launch(void* const* d_in, const int* in_sizes, int n_in,
                              void* d_out, int out_size, void* d_ws, size_t ws_size,
                              hipStream_t stream) {
    const float* preds  = (const float*)d_in[0];
    const float* target = (const float*)d_in[1];
    float* out = (float*)d_out;
    float* ws  = (float*)d_ws;

    pair_kernel<<<B * 16, 256, 0, stream>>>(preds, target, ws);
    finish_kernel<<<B, 256, 0, stream>>>(target, ws, out);
}

// Round 11
// 88.961 us; speedup vs baseline: 1.0749x; 1.0491x over previous
//
#include <hip/hip_runtime.h>

#define B 128
#define L 1024

#if __has_builtin(__builtin_amdgcn_exp2f)
#define EXP2(x) __builtin_amdgcn_exp2f(x)
#else
#define EXP2(x) __expf((x) * 0.6931471805599453f)
#endif

// ws layout (floats):
//   [0 .. 1048576)  per-block E partials: blk*1024 + i   (1024 blocks x 4KB = 4MB)
//   [1048576]       ndcg accumulator   (zeroed by pair_kernel block 0)
//   [1048577]       completion counter (zeroed by pair_kernel block 0)
#define WS_ACC  1048576
#define WS_GCTR 1048577

// erfc(|y|) ~= exp(-(1.12838 y + 0.6446 y^2 + 0.0745 y^3)), |dPhi| <= ~2.5e-4
// (constants pre-multiplied by -log2(e) for v_exp_f32). erf(y) = copysign(1-e, y).
#define K1 -1.6279072f
#define K2 -0.9299637f
#define K3 -0.1074808f

// rotate value through a 16-lane DPP row (full-rate VALU, no LDS pipe)
__device__ __forceinline__ float ror16(float x) {
    int i = __float_as_int(x);
    i = __builtin_amdgcn_update_dpp(i, i, 0x121 /*row_ror:1*/, 0xF, 0xF, true);
    return __int_as_float(i);
}

// Antisymmetric pair kernel. erf is odd => term(i,j) = -term(j,i): compute each
// unordered 16x16 group-tile ONCE via a DPP ring. 16-lane ring holds fixed i's
// (group g); the 16 j-values of group gj rotate through the ring together with
// their accumulator ej. Per rotation step each lane does one term:
//   Ei += term ; ej = ror(ej) - term  (rotation folds into the sub)
// Coverage (tournament): ring (g, half) does distances s = 0..15 (half 0) or
// s = 16..31 plus s=32 iff g<32 (half 1) -> every unordered tile exactly once.
// j-side sums deposit into an LDS ebuf (ds_add_f32; rings of a block hit
// distinct groups per step). Per-block partials PLAIN-stored to disjoint ws
// slices (R6 lesson: no device fences/atomics in the hot kernel).
// grid = B*8 blocks (4 blocks/CU, 16 waves/CU), 256 threads = 16 rings.
__global__ __launch_bounds__(256, 8) void pair_kernel(const float* __restrict__ preds,
                                                      float* __restrict__ ws) {
    __shared__ float sp[L];     // row, prescaled by 0.5 (erf argument = diff/2)
    __shared__ float ebuf[L];   // per-block E accumulation

    const int blk  = blockIdx.x;
    const int b    = blk >> 3;
    const int hb   = blk & 7;
    const int tid  = threadIdx.x;
    const int l16  = tid & 15;
    const int ring = tid >> 4;            // 0..15
    const int slot = hb * 16 + ring;      // 0..127
    const int g    = slot & 63;           // this ring's i-group
    const int half = slot >> 6;           // 0: s=0..15, 1: s=16..32

    if (blk == 0 && tid == 0) {
        ws[WS_ACC] = 0.0f;                // visible to finish_kernel at
        ((int*)ws)[WS_GCTR] = 0;          // dispatch boundary
    }

    const float* prow = preds + b * L;
    float4 v = reinterpret_cast<const float4*>(prow)[tid];
    v.x *= 0.5f; v.y *= 0.5f; v.z *= 0.5f; v.w *= 0.5f;
    reinterpret_cast<float4*>(sp)[tid] = v;
    reinterpret_cast<float4*>(ebuf)[tid] = make_float4(0.f, 0.f, 0.f, 0.f);
    __syncthreads();

    const float pi = sp[g * 16 + l16];
    float Ei = 0.0f;

    const int nt = half ? (16 + (g < 32 ? 1 : 0)) : 16;   // block-uniform
    for (int si = 0; si < nt; ++si) {
        const int s  = half ? (16 + si) : si;
        const int gj = (g + s) & 63;
        float pj = sp[gj * 16 + l16];
        float ej = 0.0f;
        #pragma unroll
        for (int k = 0; k < 16; ++k) {
            pj = ror16(pj);                          // advance ring alignment
            float d = pi - pj;
            float a = __builtin_fabsf(d);
            float t = __builtin_fmaf(K3, a, K2);
            float u = __builtin_fmaf(t, a, K1);
            float e = EXP2(a * u);                   // ~= erfc(|y|)
            float r = __builtin_copysignf(1.0f - e, d);  // erf(y)
            Ei += r;                                 // i-side
            ej = ror16(ej) - r;                      // j-side, kept ring-aligned
        }
        if (s != 0)                                  // self-tile: Ei already complete
            atomicAdd(&ebuf[gj * 16 + l16], ej);     // LDS atomic (ds_add_f32)
    }
    atomicAdd(&ebuf[g * 16 + l16], Ei);
    __syncthreads();

    // plain coalesced store of this block's partials to its disjoint slice
    float4 r4 = reinterpret_cast<float4*>(ebuf)[tid];
    reinterpret_cast<float4*>(ws + (size_t)blk * L)[tid] = r4;
}

// grid = B blocks, 256 threads. Block b: sum the 8 E-partials per i, compute
// dcg; counting-sort IDCG (grades are ints 0..4); ndcg; last block writes out.
__global__ __launch_bounds__(256) void finish_kernel(const float* __restrict__ target,
                                                     float* __restrict__ ws,
                                                     float* __restrict__ out) {
    __shared__ unsigned long long cred[256];
    __shared__ float2 fred[256];

    const int b   = blockIdx.x;
    const int tid = threadIdx.x;
    const float* trow = target + b * L;

    float dcg_p = 0.0f;
    unsigned long long cnt = 0ull;
    #pragma unroll
    for (int k = 0; k < 4; ++k) {
        const int i = tid + k * 256;
        float E = 0.0f;
        #pragma unroll
        for (int hb = 0; hb < 8; ++hb)
            E += ws[(size_t)(b * 8 + hb) * L + i];
        // sum_j Phi = L/2 + E/2 (diag term = 0 in E, Phi(0)=0.5 exact);
        // expected_rank + 1 = 513.5 + E/2
        float er1 = 513.5f + 0.5f * E;
        float t = trow[i];
        dcg_p += (EXP2(t) - 1.0f) * __builtin_amdgcn_rcpf(__log2f(er1));
        cnt += ((unsigned long long)(t > 3.5f) << 48)
             + ((unsigned long long)(t > 2.5f) << 32)
             + ((unsigned long long)(t > 1.5f) << 16)
             + ((unsigned long long)(t > 0.5f));
    }
    cred[tid] = cnt;
    __syncthreads();
    #pragma unroll
    for (int s = 128; s > 0; s >>= 1) {
        if (tid < (unsigned)s) cred[tid] += cred[tid + s];
        __syncthreads();
    }
    const unsigned long long tot = cred[0];
    const int n4 = (int)(tot >> 48) & 0xFFFF;
    const int n3 = (int)(tot >> 32) & 0xFFFF;
    const int n2 = (int)(tot >> 16) & 0xFFFF;
    const int n1 = (int)(tot)       & 0xFFFF;

    float idcg_p = 0.0f;
    #pragma unroll
    for (int k = 0; k < 4; ++k) {
        int pos = tid + 1 + k * 256;
        float gain = (pos <= n4) ? 15.0f : (pos <= n3) ? 7.0f :
                     (pos <= n2) ? 3.0f  : (pos <= n1) ? 1.0f : 0.0f;
        idcg_p += gain * __builtin_amdgcn_rcpf(__log2f((float)pos + 1.0f));
    }
    fred[tid] = make_float2(idcg_p, dcg_p);
    __syncthreads();
    #pragma unroll
    for (int s = 128; s > 0; s >>= 1) {
        if (tid < (unsigned)s) {
            float2 x = fred[tid], y = fred[tid + s];
            fred[tid] = make_float2(x.x + y.x, x.y + y.y);
        }
        __syncthreads();
    }

    if (tid == 0) {
        float ndcg = fred[0].y / (fred[0].x + 1e-10f);
        atomicAdd(&ws[WS_ACC], ndcg);
        __threadfence();
        int old = atomicAdd((int*)ws + WS_GCTR, 1);
        if (old == B - 1) {
            float acc = atomicAdd(&ws[WS_ACC], 0.0f);  // coherent read
            out[0] = -acc * (1.0f / (float)B);
        }
    }
}

extern "C" void kernel_launch(void* const* d_in, const int* in_sizes, int n_in,
                              void* d_out, int out_size, void* d_ws, size_t ws_size,
                              hipStream_t stream) {
    const float* preds  = (const float*)d_in[0];
    const float* target = (const float*)d_in[1];
    float* out = (float*)d_out;
    float* ws  = (float*)d_ws;

    pair_kernel<<<B * 8, 256, 0, stream>>>(preds, ws);
    finish_kernel<<<B, 256, 0, stream>>>(target, ws, out);
}